// Round 9
// baseline (695.799 us; speedup 1.0000x reference)
//
#include <hip/hip_runtime.h>
#include <hip/hip_bf16.h>
#include <math.h>

typedef __hip_bfloat16 bf16;
using bf16x8 = __bf16 __attribute__((ext_vector_type(8)));
using f32x4  = float  __attribute__((ext_vector_type(4)));

#define D_MODEL 2048
#define S_LEN   2048
#define NB      2
#define NH      16
#define DHEAD   128
#define DFF     8192
#define M_ROWS  (NB * S_LEN)   // 4096

__device__ __forceinline__ void gload_lds16(const void* g, void* l) {
    __builtin_amdgcn_global_load_lds((const __attribute__((address_space(1))) void*)g,
                                     (__attribute__((address_space(3))) void*)l, 16, 0, 0);
}

// ---------------------------------------------------------------------------
// LayerNorm: fp32 [rows][2048] -> bf16 [rows][2048], one block per row
// ---------------------------------------------------------------------------
__global__ __launch_bounds__(256) void ln_kernel(const float* __restrict__ x,
                                                 const float* __restrict__ gw,
                                                 const float* __restrict__ bw,
                                                 bf16* __restrict__ out) {
    const int row = blockIdx.x;
    const float* xr = x + (size_t)row * D_MODEL;
    const int tid = threadIdx.x;
    float4 v0 = ((const float4*)xr)[tid * 2];
    float4 v1 = ((const float4*)xr)[tid * 2 + 1];
    float s = v0.x + v0.y + v0.z + v0.w + v1.x + v1.y + v1.z + v1.w;
    float q = v0.x*v0.x + v0.y*v0.y + v0.z*v0.z + v0.w*v0.w
            + v1.x*v1.x + v1.y*v1.y + v1.z*v1.z + v1.w*v1.w;
    #pragma unroll
    for (int off = 32; off; off >>= 1) {
        s += __shfl_xor(s, off);
        q += __shfl_xor(q, off);
    }
    __shared__ float red[8];
    const int wid = tid >> 6;
    if ((tid & 63) == 0) { red[wid] = s; red[4 + wid] = q; }
    __syncthreads();
    s = red[0] + red[1] + red[2] + red[3];
    q = red[4] + red[5] + red[6] + red[7];
    const float mean = s * (1.0f / D_MODEL);
    const float var  = q * (1.0f / D_MODEL) - mean * mean;
    const float inv  = rsqrtf(var + 1e-5f);
    float4 g0 = ((const float4*)gw)[tid * 2];
    float4 g1 = ((const float4*)gw)[tid * 2 + 1];
    float4 b0 = ((const float4*)bw)[tid * 2];
    float4 b1 = ((const float4*)bw)[tid * 2 + 1];
    bf16* orow = out + (size_t)row * D_MODEL + tid * 8;
    orow[0] = __float2bfloat16((v0.x - mean) * inv * g0.x + b0.x);
    orow[1] = __float2bfloat16((v0.y - mean) * inv * g0.y + b0.y);
    orow[2] = __float2bfloat16((v0.z - mean) * inv * g0.z + b0.z);
    orow[3] = __float2bfloat16((v0.w - mean) * inv * g0.w + b0.w);
    orow[4] = __float2bfloat16((v1.x - mean) * inv * g1.x + b1.x);
    orow[5] = __float2bfloat16((v1.y - mean) * inv * g1.y + b1.y);
    orow[6] = __float2bfloat16((v1.z - mean) * inv * g1.z + b1.z);
    orow[7] = __float2bfloat16((v1.w - mean) * inv * g1.w + b1.w);
}

// ---------------------------------------------------------------------------
// Transpose+convert: fp32 [R][C] -> bf16 [C][R]
// ---------------------------------------------------------------------------
__global__ __launch_bounds__(256) void transpose_f2b(const float* __restrict__ in,
                                                     bf16* __restrict__ out,
                                                     int R, int C) {
    __shared__ float t[32][33];
    const int c0 = blockIdx.x * 32, r0 = blockIdx.y * 32;
    const int tx = threadIdx.x & 31, ty = threadIdx.x >> 5;
    #pragma unroll
    for (int i = ty; i < 32; i += 8) t[i][tx] = in[(size_t)(r0 + i) * C + c0 + tx];
    __syncthreads();
    #pragma unroll
    for (int i = ty; i < 32; i += 8)
        out[(size_t)(c0 + i) * R + r0 + tx] = __float2bfloat16(t[tx][i]);
}

// Per-head V transpose: bf16 [S][128] -> bf16 [128][S]
__global__ __launch_bounds__(256) void transpose_v(const bf16* __restrict__ in,
                                                   bf16* __restrict__ out) {
    const int bh = blockIdx.z;
    const bf16* ib = in + (size_t)bh * S_LEN * DHEAD;
    bf16* ob = out + (size_t)bh * DHEAD * S_LEN;
    __shared__ float t[32][33];
    const int c0 = blockIdx.x * 32;   // over DHEAD
    const int r0 = blockIdx.y * 32;   // over S
    const int tx = threadIdx.x & 31, ty = threadIdx.x >> 5;
    #pragma unroll
    for (int i = ty; i < 32; i += 8)
        t[i][tx] = __bfloat162float(ib[(size_t)(r0 + i) * DHEAD + c0 + tx]);
    __syncthreads();
    #pragma unroll
    for (int i = ty; i < 32; i += 8)
        ob[(size_t)(c0 + i) * S_LEN + r0 + tx] = __float2bfloat16(t[tx][i]);
}

// ---------------------------------------------------------------------------
// In-place RoPE on q,k; Q pre-scaled by 1/sqrt(DHEAD).
// ---------------------------------------------------------------------------
__global__ __launch_bounds__(256) void rope_kernel(bf16* __restrict__ qk,
                                                   const float* __restrict__ ct,
                                                   const float* __restrict__ st) {
    const size_t idx = (size_t)blockIdx.x * 256 + threadIdx.x;
    const int dh = (int)(idx & 63);
    const size_t rrow = idx >> 6;
    const int sidx = (int)(rrow & (S_LEN - 1));
    const int which = (int)(rrow >> 16);
    const float f = (which == 0) ? 0.08838834764831845f : 1.0f;
    bf16* p = qk + rrow * DHEAD;
    const float c  = ct[sidx * DHEAD + dh];
    const float sn = st[sidx * DHEAD + dh];
    const float x1 = __bfloat162float(p[dh]);
    const float x2 = __bfloat162float(p[dh + 64]);
    p[dh]      = __float2bfloat16((x1 * c - x2 * sn) * f);
    p[dh + 64] = __float2bfloat16((x2 * c + x1 * sn) * f);
}

// ---------------------------------------------------------------------------
// 128x128 GEMM (m97 + T2 + T1), kept for the out-projection (EPI 1 only).
// ---------------------------------------------------------------------------
template <int EPI>
__global__ __launch_bounds__(256) void gemm_kernel(const bf16* __restrict__ A,
                                                   const bf16* __restrict__ Bt,
                                                   const float* __restrict__ bias,
                                                   const float* __restrict__ resid,
                                                   void* __restrict__ outp,
                                                   int M, int N, int K, int kLen) {
    __shared__ __align__(16) bf16 As[128][64];
    __shared__ __align__(16) bf16 Bs[128][64];
    const int tid  = threadIdx.x;
    const int lane = tid & 63;
    const int wid  = tid >> 6;
    const int wr = wid >> 1, wc = wid & 1;
    const int cc = lane & 15, g = lane >> 4;
    const int csw = cc & 7;

    const int nx = gridDim.x, ny = gridDim.y, nz = gridDim.z;
    int flat = blockIdx.x + nx * (blockIdx.y + ny * blockIdx.z);
    const int nwg = nx * ny * nz;
    flat = (flat & 7) * (nwg >> 3) + (flat >> 3);
    const int bx = flat % nx;
    const int t2 = flat / nx;
    const int by = t2 % ny;
    const int bz = t2 / ny;
    const int m0 = by * 128, n0 = bx * 128;
    const int kStart = bz * kLen;

    const int srow  = lane >> 3;
    const int sslot = (lane & 7) ^ (srow & 7);
    const int sb    = sslot * 16;

    f32x4 acc[4][4];
    const f32x4 zero = {0.f, 0.f, 0.f, 0.f};
    #pragma unroll
    for (int i = 0; i < 4; i++)
        #pragma unroll
        for (int j = 0; j < 4; j++) acc[i][j] = zero;

    const char* gA = (const char*)A  + ((size_t)(m0 + wid * 32 + srow) * K) * 2 + sb;
    const char* gB = (const char*)Bt + ((size_t)(n0 + wid * 32 + srow) * K) * 2 + sb;
    char* lA = (char*)&As[0][0] + wid * 4096;
    char* lB = (char*)&Bs[0][0] + wid * 4096;
    const size_t rowK2 = (size_t)K * 2;

    for (int k0 = kStart; k0 < kStart + kLen; k0 += 64) {
        #pragma unroll
        for (int c = 0; c < 4; ++c) {
            gload_lds16(gA + (size_t)k0 * 2 + (size_t)c * 8 * rowK2, lA + c * 1024);
            gload_lds16(gB + (size_t)k0 * 2 + (size_t)c * 8 * rowK2, lB + c * 1024);
        }
        __syncthreads();
        #pragma unroll
        for (int kh = 0; kh < 2; kh++) {
            const int ux = ((kh * 4 + g) ^ csw) << 4;
            bf16x8 af[4], bfm[4];
            #pragma unroll
            for (int mi = 0; mi < 4; mi++)
                af[mi]  = *(const bf16x8*)((const char*)&As[wr * 64 + mi * 16 + cc][0] + ux);
            #pragma unroll
            for (int ni = 0; ni < 4; ni++)
                bfm[ni] = *(const bf16x8*)((const char*)&Bs[wc * 64 + ni * 16 + cc][0] + ux);
            #pragma unroll
            for (int mi = 0; mi < 4; mi++)
                #pragma unroll
                for (int ni = 0; ni < 4; ni++)
                    acc[mi][ni] = __builtin_amdgcn_mfma_f32_16x16x32_bf16(af[mi], bfm[ni], acc[mi][ni], 0, 0, 0);
        }
        __syncthreads();
    }

    #pragma unroll
    for (int mi = 0; mi < 4; mi++) {
        #pragma unroll
        for (int ni = 0; ni < 4; ni++) {
            const int colb = n0 + wc * 64 + ni * 16 + cc;
            const float bcol = bias[colb];
            #pragma unroll
            for (int r = 0; r < 4; r++) {
                const int row = m0 + wr * 64 + mi * 16 + g * 4 + r;
                const float v = acc[mi][ni][r] + bcol;
                float* o = (float*)outp;
                o[(size_t)row * N + colb] = v + resid[(size_t)row * N + colb];
            }
        }
    }
}

// ---------------------------------------------------------------------------
// 256x256 GEMM (T1+T2+T3+T4+T5), read-once operands + DEEP PREFETCH:
// ALL 4 half-tiles of tile t+1 are staged in one burst at the tile HEAD,
// followed by the tile's single vmcnt(8)+barrier — which waits for tile t's
// 8 loads issued one full tile (4 phases ~ 1000 cyc) earlier, covering HBM
// miss latency. Phases p1-p4 then run with no vmem waits:
//   p1 {read A0,B0 -> MFMA q00} p2 {read B1 -> q01} p3 {read A1 -> q11}
//   p4 {q10, held regs, no reads}.
// Hazards: fill->read = head vmcnt+barrier (per-wave vmcnt propagated by
// barrier); read->refill WAR = p3-end barrier (all PB reads retire before
// it; next write to PB staged a full tile later). Last tile peeled, vmcnt(0).
// ---------------------------------------------------------------------------
template <int EPI>
__global__ __launch_bounds__(512, 2) void gemm256(const bf16* __restrict__ A,
                                                  const bf16* __restrict__ Bt,
                                                  const float* __restrict__ bias,
                                                  void* __restrict__ outp,
                                                  int M, int N, int K, int kLen) {
    __shared__ __align__(16) bf16 lds[2][2][2][128][64];   // 128 KiB
    const int tid  = threadIdx.x;
    const int lane = tid & 63;
    const int wid  = tid >> 6;
    const int wave_m = wid >> 2, wave_n = wid & 3;
    const int wm16 = wave_m * 16, wn16 = wave_n * 16;
    const int cc = lane & 15, g = lane >> 4;
    const int csw = cc & 7;

    const int nx = gridDim.x, ny = gridDim.y, nz = gridDim.z;
    int flat = blockIdx.x + nx * (blockIdx.y + ny * blockIdx.z);
    const int nwg = nx * ny * nz;
    flat = (flat & 7) * (nwg >> 3) + (flat >> 3);
    const int bx = flat % nx;
    const int t2 = flat / nx;
    const int by = t2 % ny;
    const int bz = t2 / ny;
    const int m0 = by * 256, n0 = bx * 256;
    const int kStart = bz * kLen;
    const int NT = kLen >> 6;           // even, >= 4

    // staging geometry: per half-tile each thread issues 2 16B loads
    const int srow_lo = tid >> 3;                       // 0..63
    const int sbyte   = ((tid & 7) ^ (srow_lo & 7)) * 16;
    const size_t rowB  = (size_t)K * 2;
    const size_t halfB = rowB * 128;
    const size_t jB    = rowB * 64;
    const char* sA = (const char*)A  + (size_t)(m0 + srow_lo) * rowB + sbyte;
    const char* sB = (const char*)Bt + (size_t)(n0 + srow_lo) * rowB + sbyte;

#define STAGE(SOP, SMH, P, K0) do {                                           \
    const char* _s = (SOP ? sB : sA) + (size_t)(SMH) * halfB + (size_t)(K0) * 2; \
    char* _d = ((char*)&lds[P][SOP][SMH][0][0]) + wid * 1024;                 \
    gload_lds16(_s, _d);                                                      \
    gload_lds16(_s + jB, _d + 8192);                                          \
} while (0)

    f32x4 acc[8][4];
    const f32x4 zero = {0.f, 0.f, 0.f, 0.f};
    #pragma unroll
    for (int i = 0; i < 8; i++)
        #pragma unroll
        for (int j = 0; j < 4; j++) acc[i][j] = zero;

    bf16x8 aR[2][4], bR0[2][2], bR1[2][2];

#define LDA(PB, MH, MI, UX) (*(const bf16x8*)((const char*)&lds[PB][0][MH][(MI) * 32 + wm16 + cc][0] + (UX)))
#define LDB(PB, NH, NI, UX) (*(const bf16x8*)((const char*)&lds[PB][1][NH][(NI) * 64 + wn16 + cc][0] + (UX)))
#define MFMA(a, b, c) __builtin_amdgcn_mfma_f32_16x16x32_bf16(a, b, c, 0, 0, 0)

#define BAR() do {                                                            \
    __builtin_amdgcn_sched_barrier(0);                                        \
    __builtin_amdgcn_s_barrier();                                             \
    __builtin_amdgcn_sched_barrier(0);                                        \
} while (0)

#define MMQ(MB, NB_, AHR, BHR) do {                                           \
    __builtin_amdgcn_s_setprio(1);                                            \
    _Pragma("unroll")                                                         \
    for (int kk = 0; kk < 2; ++kk)                                            \
        _Pragma("unroll")                                                     \
        for (int mi = 0; mi < 4; ++mi)                                        \
            _Pragma("unroll")                                                 \
            for (int ni = 0; ni < 2; ++ni)                                    \
                acc[(MB) + mi][(NB_) + ni] =                                  \
                    MFMA(AHR[kk][mi], BHR[kk][ni], acc[(MB) + mi][(NB_) + ni]); \
    __builtin_amdgcn_s_setprio(0);                                            \
} while (0)

// tile head: burst-stage all of tile t+1, then single per-tile wait for
// tile t's loads (issued one full tile earlier).
#define TILEHEAD(PB, DOST, K0N, VN) do {                                      \
    if (DOST) {                                                               \
        STAGE(0, 0, (PB) ^ 1, K0N);                                           \
        STAGE(1, 0, (PB) ^ 1, K0N);                                           \
        STAGE(0, 1, (PB) ^ 1, K0N);                                           \
        STAGE(1, 1, (PB) ^ 1, K0N);                                           \
    }                                                                         \
    __builtin_amdgcn_sched_barrier(0);                                        \
    asm volatile("s_waitcnt vmcnt(" VN ")" ::: "memory");                     \
    __builtin_amdgcn_s_barrier();                                             \
    __builtin_amdgcn_sched_barrier(0);                                        \
} while (0)

#define TILEBODY(PB) do {                                                     \
    /* p1: read A0 + B0; MFMA q(0,0) */                                       \
    _Pragma("unroll")                                                         \
    for (int kk = 0; kk < 2; ++kk) {                                          \
        const int ux = ((kk * 4 + g) ^ csw) << 4;                             \
        _Pragma("unroll")                                                     \
        for (int mi = 0; mi < 4; ++mi) aR[kk][mi] = LDA(PB, 0, mi, ux);       \
        _Pragma("unroll")                                                     \
        for (int ni = 0; ni < 2; ++ni) bR0[kk][ni] = LDB(PB, 0, ni, ux);      \
    }                                                                         \
    MMQ(0, 0, aR, bR0);                                                       \
    BAR();                                                                    \
    /* p2: read B1; MFMA q(0,1) with held A0 */                               \
    _Pragma("unroll")                                                         \
    for (int kk = 0; kk < 2; ++kk) {                                          \
        const int ux = ((kk * 4 + g) ^ csw) << 4;                             \
        _Pragma("unroll")                                                     \
        for (int ni = 0; ni < 2; ++ni) bR1[kk][ni] = LDB(PB, 1, ni, ux);      \
    }                                                                         \
    MMQ(0, 2, aR, bR1);                                                       \
    BAR();                                                                    \
    /* p3: read A1; MFMA q(1,1) with held B1 */                               \
    _Pragma("unroll")                                                         \
    for (int kk = 0; kk < 2; ++kk) {                                          \
        const int ux = ((kk * 4 + g) ^ csw) << 4;                             \
        _Pragma("unroll")                                                     \
        for (int mi = 0; mi < 4; ++mi) aR[kk][mi] = LDA(PB, 1, mi, ux);       \
    }                                                                         \
    MMQ(4, 2, aR, bR1);                                                       \
    BAR();                                                                    \
    /* p4: no reads; MFMA q(1,0) with held A1 + held B0; no trailing bar */   \
    MMQ(4, 0, aR, bR0);                                                       \
} while (0)

    // prologue: burst-stage tile 0 into buffer 0 (8 loads)
    STAGE(0, 0, 0, kStart);
    STAGE(1, 0, 0, kStart);
    STAGE(0, 1, 0, kStart);
    STAGE(1, 1, 0, kStart);

    // steady state in pairs (compile-time buffer index); tiles 0..NT-3
    for (int tt = 0; tt < (NT - 2) / 2; ++tt) {
        TILEHEAD(0, true, kStart + (2 * tt + 1) * 64, "8");
        TILEBODY(0);
        TILEHEAD(1, true, kStart + (2 * tt + 2) * 64, "8");
        TILEBODY(1);
    }
    // tile NT-2 (buffer 0), stages the last tile
    TILEHEAD(0, true, kStart + (NT - 1) * 64, "8");
    TILEBODY(0);
    // peeled last tile (buffer 1): full drain, no staging
    TILEHEAD(1, false, 0, "0");
    TILEBODY(1);

#undef TILEBODY
#undef TILEHEAD
#undef MMQ
#undef BAR
#undef LDA
#undef LDB
#undef MFMA
#undef STAGE

    #pragma unroll
    for (int ai = 0; ai < 8; ai++) {
        const int rowb = m0 + (ai >> 2) * 128 + (ai & 3) * 32 + wm16 + g * 4;
        #pragma unroll
        for (int bj = 0; bj < 4; bj++) {
            const int colb = n0 + (bj >> 1) * 128 + (bj & 1) * 64 + wn16 + cc;
            const float bcol = (EPI == 3) ? 0.0f : bias[colb];
            #pragma unroll
            for (int r = 0; r < 4; r++) {
                const int row = rowb + r;
                const float v = acc[ai][bj][r] + bcol;
                if (EPI == 0) {
                    const int which = colb >> 11;
                    const int h     = (colb >> 7) & 15;
                    const int dh    = colb & 127;
                    const int b     = row >> 11;
                    const int sidx  = row & (S_LEN - 1);
                    bf16* o = (bf16*)outp;
                    o[((size_t)(which * 32 + b * 16 + h) * S_LEN + sidx) * DHEAD + dh] = __float2bfloat16(v);
                } else if (EPI == 2) {
                    bf16* o = (bf16*)outp;
                    const float gel = 0.5f * v * (1.0f + erff(v * 0.70710678118f));
                    o[(size_t)row * N + colb] = __float2bfloat16(gel);
                } else {
                    float* o = (float*)outp + (size_t)bz * M * N;
                    o[(size_t)row * N + colb] = v;
                }
            }
        }
    }
}

// ---------------------------------------------------------------------------
// FF2 split-K combine: out += p0 + p1 + bias   (out holds x2 residual)
// ---------------------------------------------------------------------------
__global__ __launch_bounds__(256) void ff2_combine(const float* __restrict__ p,
                                                   const float* __restrict__ bias,
                                                   float* __restrict__ out) {
    const size_t i4 = (size_t)blockIdx.x * 256 + threadIdx.x;
    const float4 a  = ((const float4*)out)[i4];
    const float4 p0 = ((const float4*)p)[i4];
    const float4 p1 = ((const float4*)(p + (size_t)M_ROWS * D_MODEL))[i4];
    const float4 b  = ((const float4*)bias)[i4 & (D_MODEL / 4 - 1)];
    float4 r;
    r.x = a.x + p0.x + p1.x + b.x;
    r.y = a.y + p0.y + p1.y + b.y;
    r.z = a.z + p0.z + p1.z + b.z;
    r.w = a.w + p0.w + p1.w + b.w;
    ((float4*)out)[i4] = r;
}

// ---------------------------------------------------------------------------
// Flash attention, causal, max-free (unchanged).
// ---------------------------------------------------------------------------
__global__ __launch_bounds__(256) void attn_kernel(const bf16* __restrict__ q,
                                                   const bf16* __restrict__ k,
                                                   const bf16* __restrict__ vT,
                                                   bf16* __restrict__ aout) {
    int flat = blockIdx.x + gridDim.x * blockIdx.y;
    const int nwg = gridDim.x * gridDim.y;
    flat = (flat & 7) * (nwg >> 3) + (flat >> 3);
    const int qt = (int)(gridDim.x - 1 - (flat % gridDim.x));
    const int bh = flat / gridDim.x;
    const int tid = threadIdx.x;
    const int lane = tid & 63, wid = tid >> 6;
    const int cc = lane & 15, g = lane >> 4;
    const int csw = cc & 7;
    const int q0 = qt * 64;
    const int q0w = q0 + wid * 16;
    const bf16* qb = q  + (size_t)bh * S_LEN * DHEAD;
    const char* kb2 = (const char*)(k  + (size_t)bh * S_LEN * DHEAD);
    const char* vb2 = (const char*)(vT + (size_t)bh * DHEAD * S_LEN);

    __shared__ __align__(16) bf16 Ks[2][64][128];
    __shared__ __align__(16) bf16 Vs[2][128][64];
    __shared__ __align__(16) bf16 Ps[4][16][72];

    const int kst_row = wid * 4 + (lane >> 4);
    const int kst_sl  = (lane & 15) ^ (kst_row & 7);
    const int vst_row = wid * 8 + (lane >> 3);
    const int vst_sl  = (lane & 7) ^ (vst_row & 7);

    bf16x8 qf[4];
    #pragma unroll
    for (int kk = 0; kk < 4; kk++)
        qf[kk] = *(const bf16x8*)(qb + (size_t)(q0w + cc) * DHEAD + kk * 32 + g * 8);

    f32x4 oacc[8];
    const f32x4 zero = {0.f, 0.f, 0.f, 0.f};
    #pragma unroll
    for (int d = 0; d < 8; d++) oacc[d] = zero;
    float lsum[4] = {0.f, 0.f, 0.f, 0.f};

    {
        char* ksl = (char*)&Ks[0][0][0] + wid * 1024;
        char* vsl = (char*)&Vs[0][0][0] + wid * 1024;
        #pragma unroll
        for (int i = 0; i < 4; ++i) {
            gload_lds16(kb2 + (size_t)(kst_row + i * 16) * 256 + kst_sl * 16, ksl + i * 4096);
            gload_lds16(vb2 + (size_t)(vst_row + i * 32) * (S_LEN * 2) + vst_sl * 16, vsl + i * 4096);
        }
    }
    asm volatile("s_waitcnt vmcnt(0)" ::: "memory");
    __syncthreads();

    int cur = 0;
    for (int kt = 0; kt <= qt; ++kt) {
        const int kv0 = kt * 64;
        if (kt < qt) {
            const int nv0 = kv0 + 64;
            char* ksl = (char*)&Ks[cur ^ 1][0][0] + wid * 1024;
            char* vsl = (char*)&Vs[cur ^ 1][0][0] + wid * 1024;
            #pragma unroll
            for (int i = 0; i < 4; ++i) {
                gload_lds16(kb2 + (size_t)(nv0 + kst_row + i * 16) * 256 + kst_sl * 16, ksl + i * 4096);
                gload_lds16(vb2 + (size_t)(vst_row + i * 32) * (S_LEN * 2) + (size_t)nv0 * 2 + vst_sl * 16, vsl + i * 4096);
            }
        }

        f32x4 sacc[4];
        #pragma unroll
        for (int ni = 0; ni < 4; ni++) sacc[ni] = zero;
        __builtin_amdgcn_s_setprio(1);
        #pragma unroll
        for (int kk = 0; kk < 4; kk++) {
            const int ux = ((kk * 4 + g) ^ csw) << 4;
            #pragma unroll
            for (int ni = 0; ni < 4; ni++) {
                const bf16x8 kf = *(const bf16x8*)((const char*)&Ks[cur][ni * 16 + cc][0] + ux);
                sacc[ni] = __builtin_amdgcn_mfma_f32_16x16x32_bf16(qf[kk], kf, sacc[ni], 0, 0, 0);
            }
        }
        __builtin_amdgcn_s_setprio(0);

        #pragma unroll
        for (int r = 0; r < 4; r++) {
            const int qrow = q0w + g * 4 + r;
            float p[4];
            #pragma unroll
            for (int ni = 0; ni < 4; ni++) {
                const float sv = (kv0 + ni * 16 + cc <= qrow) ? sacc[ni][r] : -1e30f;
                p[ni] = __expf(sv);
            }
            lsum[r] += (p[0] + p[1]) + (p[2] + p[3]);
            #pragma unroll
            for (int ni = 0; ni < 4; ni++)
                Ps[wid][g * 4 + r][ni * 16 + cc] = __float2bfloat16(p[ni]);
        }

        __builtin_amdgcn_s_setprio(1);
        #pragma unroll
        for (int ks = 0; ks < 2; ks++) {
            const bf16x8 pf = *(const bf16x8*)(&Ps[wid][cc][ks * 32 + g * 8]);
            const int ux = ((ks * 4 + g) ^ csw) << 4;
            #pragma unroll
            for (int d = 0; d < 8; d++) {
                const bf16x8 vf = *(const bf16x8*)((const char*)&Vs[cur][d * 16 + cc][0] + ux);
                oacc[d] = __builtin_amdgcn_mfma_f32_16x16x32_bf16(pf, vf, oacc[d], 0, 0, 0);
            }
        }
        __builtin_amdgcn_s_setprio(0);

        asm volatile("s_waitcnt vmcnt(0)" ::: "memory");
        __syncthreads();
        cur ^= 1;
    }

    const int b = bh >> 4, h = bh & 15;
    #pragma unroll
    for (int r = 0; r < 4; r++) {
        float rs = lsum[r];
        #pragma unroll
        for (int off = 1; off < 16; off <<= 1) rs += __shfl_xor(rs, off);
        const float invl = 1.0f / rs;
        const int srow = q0w + g * 4 + r;
        bf16* orow = aout + ((size_t)(b * S_LEN + srow)) * D_MODEL + h * DHEAD;
        #pragma unroll
        for (int d = 0; d < 8; d++) orow[d * 16 + cc] = __float2bfloat16(oacc[d][r] * invl);
    }
}

// ---------------------------------------------------------------------------
extern "C" void kernel_launch(void* const* d_in, const int* in_sizes, int n_in,
                              void* d_out, int out_size, void* d_ws, size_t ws_size,
                              hipStream_t stream) {
    (void)in_sizes; (void)n_in; (void)out_size; (void)ws_size;
    const float* x      = (const float*)d_in[0];
    const float* cosb   = (const float*)d_in[1];
    const float* sinb   = (const float*)d_in[2];
    const float* ln1_g  = (const float*)d_in[4];
    const float* ln1_b  = (const float*)d_in[5];
    const float* w_qkv  = (const float*)d_in[6];
    const float* b_qkv  = (const float*)d_in[7];
    const float* w_out  = (const float*)d_in[8];
    const float* b_out  = (const float*)d_in[9];
    const float* ln2_g  = (const float*)d_in[10];
    const float* ln2_b  = (const float*)d_in[11];
    const float* w_ff1  = (const float*)d_in[12];
    const float* b_ff1  = (const float*)d_in[13];
    const float* w_ff2  = (const float*)d_in[14];
    const float* b_ff2  = (const float*)d_in[15];
    float* out = (float*)d_out;

    char* ws = (char*)d_ws;
    bf16* wT_qkv = (bf16*)(ws + 0);            // [6144][2048]  (dead by FF2)
    bf16* wT_out = (bf16*)(ws + 25165824);     // [2048][2048]  (dead by FF2)
    bf16* wT_ff1 = (bf16*)(ws + 33554432);     // [8192][2048]  (dead by FF2)
    bf16* wT_ff2 = (bf16*)(ws + 67108864);     // [2048][8192]
    bf16* xn     = (bf16*)(ws + 100663296);    // [4096][2048]
    bf16* qkv    = (bf16*)(ws + 117440512);    // [3][32][2048][128]
    bf16* aoutb  = (bf16*)(ws + 167772160);    // [4096][2048]
    bf16* vTb    = (bf16*)(ws + 184549376);    // [32][128][2048]
    bf16* hbuf   = (bf16*)(ws + 117440512);    // [4096][8192] aliases qkv+aoutb
    float* partial = (float*)(ws + 0);         // [2][4096][2048] fp32, FF2 split-K
    bf16* kbuf = qkv + (size_t)32 * S_LEN * DHEAD;
    bf16* vbuf = qkv + (size_t)64 * S_LEN * DHEAD;

    transpose_f2b<<<dim3(192, 64),  256, 0, stream>>>(w_qkv, wT_qkv, 2048, 6144);
    transpose_f2b<<<dim3(64, 64),   256, 0, stream>>>(w_out, wT_out, 2048, 2048);
    transpose_f2b<<<dim3(256, 64),  256, 0, stream>>>(w_ff1, wT_ff1, 2048, 8192);
    transpose_f2b<<<dim3(64, 256),  256, 0, stream>>>(w_ff2, wT_ff2, 8192, 2048);

    ln_kernel<<<M_ROWS, 256, 0, stream>>>(x, ln1_g, ln1_b, xn);
    gemm256<0><<<dim3(24, 16), 512, 0, stream>>>(xn, wT_qkv, b_qkv, qkv, M_ROWS, 6144, 2048, 2048);
    rope_kernel<<<32768, 256, 0, stream>>>(qkv, cosb, sinb);
    transpose_v<<<dim3(4, 64, 32), 256, 0, stream>>>(vbuf, vTb);
    attn_kernel<<<dim3(32, 32), 256, 0, stream>>>(qkv, kbuf, vTb, aoutb);
    gemm_kernel<1><<<dim3(16, 32), 256, 0, stream>>>(aoutb, wT_out, b_out, x, out, M_ROWS, 2048, 2048, 2048);
    ln_kernel<<<M_ROWS, 256, 0, stream>>>(out, ln2_g, ln2_b, xn);
    gemm256<2><<<dim3(32, 16), 512, 0, stream>>>(xn, wT_ff1, b_ff1, hbuf, M_ROWS, DFF, 2048, 2048);
    gemm256<3><<<dim3(8, 16, 2), 512, 0, stream>>>(hbuf, wT_ff2, nullptr, partial, M_ROWS, 2048, 8192, 4096);
    ff2_combine<<<8192, 256, 0, stream>>>(partial, b_ff2, out);
}

// Round 11
// 662.748 us; speedup vs baseline: 1.0499x; 1.0499x over previous
//
#include <hip/hip_runtime.h>
#include <hip/hip_bf16.h>
#include <math.h>

typedef __hip_bfloat16 bf16;
using bf16x8 = __bf16 __attribute__((ext_vector_type(8)));
using f32x4  = float  __attribute__((ext_vector_type(4)));

#define D_MODEL 2048
#define S_LEN   2048
#define NB      2
#define NH      16
#define DHEAD   128
#define DFF     8192
#define M_ROWS  (NB * S_LEN)   // 4096

__device__ __forceinline__ void gload_lds16(const void* g, void* l) {
    __builtin_amdgcn_global_load_lds((const __attribute__((address_space(1))) void*)g,
                                     (__attribute__((address_space(3))) void*)l, 16, 0, 0);
}

// ---------------------------------------------------------------------------
// LayerNorm: fp32 [rows][2048] -> bf16 [rows][2048], one block per row
// ---------------------------------------------------------------------------
__global__ __launch_bounds__(256) void ln_kernel(const float* __restrict__ x,
                                                 const float* __restrict__ gw,
                                                 const float* __restrict__ bw,
                                                 bf16* __restrict__ out) {
    const int row = blockIdx.x;
    const float* xr = x + (size_t)row * D_MODEL;
    const int tid = threadIdx.x;
    float4 v0 = ((const float4*)xr)[tid * 2];
    float4 v1 = ((const float4*)xr)[tid * 2 + 1];
    float s = v0.x + v0.y + v0.z + v0.w + v1.x + v1.y + v1.z + v1.w;
    float q = v0.x*v0.x + v0.y*v0.y + v0.z*v0.z + v0.w*v0.w
            + v1.x*v1.x + v1.y*v1.y + v1.z*v1.z + v1.w*v1.w;
    #pragma unroll
    for (int off = 32; off; off >>= 1) {
        s += __shfl_xor(s, off);
        q += __shfl_xor(q, off);
    }
    __shared__ float red[8];
    const int wid = tid >> 6;
    if ((tid & 63) == 0) { red[wid] = s; red[4 + wid] = q; }
    __syncthreads();
    s = red[0] + red[1] + red[2] + red[3];
    q = red[4] + red[5] + red[6] + red[7];
    const float mean = s * (1.0f / D_MODEL);
    const float var  = q * (1.0f / D_MODEL) - mean * mean;
    const float inv  = rsqrtf(var + 1e-5f);
    float4 g0 = ((const float4*)gw)[tid * 2];
    float4 g1 = ((const float4*)gw)[tid * 2 + 1];
    float4 b0 = ((const float4*)bw)[tid * 2];
    float4 b1 = ((const float4*)bw)[tid * 2 + 1];
    bf16* orow = out + (size_t)row * D_MODEL + tid * 8;
    orow[0] = __float2bfloat16((v0.x - mean) * inv * g0.x + b0.x);
    orow[1] = __float2bfloat16((v0.y - mean) * inv * g0.y + b0.y);
    orow[2] = __float2bfloat16((v0.z - mean) * inv * g0.z + b0.z);
    orow[3] = __float2bfloat16((v0.w - mean) * inv * g0.w + b0.w);
    orow[4] = __float2bfloat16((v1.x - mean) * inv * g1.x + b1.x);
    orow[5] = __float2bfloat16((v1.y - mean) * inv * g1.y + b1.y);
    orow[6] = __float2bfloat16((v1.z - mean) * inv * g1.z + b1.z);
    orow[7] = __float2bfloat16((v1.w - mean) * inv * g1.w + b1.w);
}

// ---------------------------------------------------------------------------
// Transpose+convert: fp32 [R][C] -> bf16 [C][R]
// ---------------------------------------------------------------------------
__global__ __launch_bounds__(256) void transpose_f2b(const float* __restrict__ in,
                                                     bf16* __restrict__ out,
                                                     int R, int C) {
    __shared__ float t[32][33];
    const int c0 = blockIdx.x * 32, r0 = blockIdx.y * 32;
    const int tx = threadIdx.x & 31, ty = threadIdx.x >> 5;
    #pragma unroll
    for (int i = ty; i < 32; i += 8) t[i][tx] = in[(size_t)(r0 + i) * C + c0 + tx];
    __syncthreads();
    #pragma unroll
    for (int i = ty; i < 32; i += 8)
        out[(size_t)(c0 + i) * R + r0 + tx] = __float2bfloat16(t[tx][i]);
}

// Per-head V transpose: bf16 [S][128] -> bf16 [128][S]
__global__ __launch_bounds__(256) void transpose_v(const bf16* __restrict__ in,
                                                   bf16* __restrict__ out) {
    const int bh = blockIdx.z;
    const bf16* ib = in + (size_t)bh * S_LEN * DHEAD;
    bf16* ob = out + (size_t)bh * DHEAD * S_LEN;
    __shared__ float t[32][33];
    const int c0 = blockIdx.x * 32;   // over DHEAD
    const int r0 = blockIdx.y * 32;   // over S
    const int tx = threadIdx.x & 31, ty = threadIdx.x >> 5;
    #pragma unroll
    for (int i = ty; i < 32; i += 8)
        t[i][tx] = __bfloat162float(ib[(size_t)(r0 + i) * DHEAD + c0 + tx]);
    __syncthreads();
    #pragma unroll
    for (int i = ty; i < 32; i += 8)
        ob[(size_t)(c0 + i) * S_LEN + r0 + tx] = __float2bfloat16(t[tx][i]);
}

// ---------------------------------------------------------------------------
// 128x128 GEMM (m97 + T2 + T1), kept for the out-projection (EPI 1 only).
// ---------------------------------------------------------------------------
template <int EPI>
__global__ __launch_bounds__(256) void gemm_kernel(const bf16* __restrict__ A,
                                                   const bf16* __restrict__ Bt,
                                                   const float* __restrict__ bias,
                                                   const float* __restrict__ resid,
                                                   void* __restrict__ outp,
                                                   int M, int N, int K, int kLen) {
    __shared__ __align__(16) bf16 As[128][64];
    __shared__ __align__(16) bf16 Bs[128][64];
    const int tid  = threadIdx.x;
    const int lane = tid & 63;
    const int wid  = tid >> 6;
    const int wr = wid >> 1, wc = wid & 1;
    const int cc = lane & 15, g = lane >> 4;
    const int csw = cc & 7;

    const int nx = gridDim.x, ny = gridDim.y, nz = gridDim.z;
    int flat = blockIdx.x + nx * (blockIdx.y + ny * blockIdx.z);
    const int nwg = nx * ny * nz;
    flat = (flat & 7) * (nwg >> 3) + (flat >> 3);
    const int bx = flat % nx;
    const int t2 = flat / nx;
    const int by = t2 % ny;
    const int bz = t2 / ny;
    const int m0 = by * 128, n0 = bx * 128;
    const int kStart = bz * kLen;

    const int srow  = lane >> 3;
    const int sslot = (lane & 7) ^ (srow & 7);
    const int sb    = sslot * 16;

    f32x4 acc[4][4];
    const f32x4 zero = {0.f, 0.f, 0.f, 0.f};
    #pragma unroll
    for (int i = 0; i < 4; i++)
        #pragma unroll
        for (int j = 0; j < 4; j++) acc[i][j] = zero;

    const char* gA = (const char*)A  + ((size_t)(m0 + wid * 32 + srow) * K) * 2 + sb;
    const char* gB = (const char*)Bt + ((size_t)(n0 + wid * 32 + srow) * K) * 2 + sb;
    char* lA = (char*)&As[0][0] + wid * 4096;
    char* lB = (char*)&Bs[0][0] + wid * 4096;
    const size_t rowK2 = (size_t)K * 2;

    for (int k0 = kStart; k0 < kStart + kLen; k0 += 64) {
        #pragma unroll
        for (int c = 0; c < 4; ++c) {
            gload_lds16(gA + (size_t)k0 * 2 + (size_t)c * 8 * rowK2, lA + c * 1024);
            gload_lds16(gB + (size_t)k0 * 2 + (size_t)c * 8 * rowK2, lB + c * 1024);
        }
        __syncthreads();
        #pragma unroll
        for (int kh = 0; kh < 2; kh++) {
            const int ux = ((kh * 4 + g) ^ csw) << 4;
            bf16x8 af[4], bfm[4];
            #pragma unroll
            for (int mi = 0; mi < 4; mi++)
                af[mi]  = *(const bf16x8*)((const char*)&As[wr * 64 + mi * 16 + cc][0] + ux);
            #pragma unroll
            for (int ni = 0; ni < 4; ni++)
                bfm[ni] = *(const bf16x8*)((const char*)&Bs[wc * 64 + ni * 16 + cc][0] + ux);
            #pragma unroll
            for (int mi = 0; mi < 4; mi++)
                #pragma unroll
                for (int ni = 0; ni < 4; ni++)
                    acc[mi][ni] = __builtin_amdgcn_mfma_f32_16x16x32_bf16(af[mi], bfm[ni], acc[mi][ni], 0, 0, 0);
        }
        __syncthreads();
    }

    #pragma unroll
    for (int mi = 0; mi < 4; mi++) {
        #pragma unroll
        for (int ni = 0; ni < 4; ni++) {
            const int colb = n0 + wc * 64 + ni * 16 + cc;
            const float bcol = bias[colb];
            #pragma unroll
            for (int r = 0; r < 4; r++) {
                const int row = m0 + wr * 64 + mi * 16 + g * 4 + r;
                const float v = acc[mi][ni][r] + bcol;
                float* o = (float*)outp;
                o[(size_t)row * N + colb] = v + resid[(size_t)row * N + colb];
            }
        }
    }
}

// ---------------------------------------------------------------------------
// 256x256 GEMM (T1+T2+T3+T4+T5), READ-ONCE operands, round-8 verified
// schedule: phases (A0,B0)->(A0,B1)->(A1,B1)->(A1,B0), one STAGE (2 loads)
// per phase (order A0,B0,A1,B1 of tile t+1), counted vmcnt 2,4,6,4;
// prologue vmcnt(4); last tile peeled with full drains (round-6 lesson).
// EPI 0: QKV-scatter with FUSED RoPE (+1/sqrt(128) on q). EPI 2: GELU.
// EPI 3: bf16 split-K partial.
// ---------------------------------------------------------------------------
template <int EPI>
__global__ __launch_bounds__(512, 2) void gemm256(const bf16* __restrict__ A,
                                                  const bf16* __restrict__ Bt,
                                                  const float* __restrict__ bias,
                                                  const float* __restrict__ ct,
                                                  const float* __restrict__ st,
                                                  void* __restrict__ outp,
                                                  int M, int N, int K, int kLen) {
    __shared__ __align__(16) bf16 lds[2][2][2][128][64];   // 128 KiB
    const int tid  = threadIdx.x;
    const int lane = tid & 63;
    const int wid  = tid >> 6;
    const int wave_m = wid >> 2, wave_n = wid & 3;
    const int wm16 = wave_m * 16, wn16 = wave_n * 16;
    const int cc = lane & 15, g = lane >> 4;
    const int csw = cc & 7;

    const int nx = gridDim.x, ny = gridDim.y, nz = gridDim.z;
    int flat = blockIdx.x + nx * (blockIdx.y + ny * blockIdx.z);
    const int nwg = nx * ny * nz;
    flat = (flat & 7) * (nwg >> 3) + (flat >> 3);
    const int bx = flat % nx;
    const int t2 = flat / nx;
    const int by = t2 % ny;
    const int bz = t2 / ny;
    const int m0 = by * 256, n0 = bx * 256;
    const int kStart = bz * kLen;
    const int NT = kLen >> 6;           // even, >= 4

    const int srow_lo = tid >> 3;                       // 0..63
    const int sbyte   = ((tid & 7) ^ (srow_lo & 7)) * 16;
    const size_t rowB  = (size_t)K * 2;
    const size_t halfB = rowB * 128;
    const size_t jB    = rowB * 64;
    const char* sA = (const char*)A  + (size_t)(m0 + srow_lo) * rowB + sbyte;
    const char* sB = (const char*)Bt + (size_t)(n0 + srow_lo) * rowB + sbyte;

#define STAGE(SOP, SMH, P, K0) do {                                           \
    const char* _s = (SOP ? sB : sA) + (size_t)(SMH) * halfB + (size_t)(K0) * 2; \
    char* _d = ((char*)&lds[P][SOP][SMH][0][0]) + wid * 1024;                 \
    gload_lds16(_s, _d);                                                      \
    gload_lds16(_s + jB, _d + 8192);                                          \
} while (0)

    f32x4 acc[8][4];
    const f32x4 zero = {0.f, 0.f, 0.f, 0.f};
    #pragma unroll
    for (int i = 0; i < 8; i++)
        #pragma unroll
        for (int j = 0; j < 4; j++) acc[i][j] = zero;

    bf16x8 aR[2][4], bR0[2][2], bR1[2][2];

#define LDA(PB, MH, MI, UX) (*(const bf16x8*)((const char*)&lds[PB][0][MH][(MI) * 32 + wm16 + cc][0] + (UX)))
#define LDB(PB, NH, NI, UX) (*(const bf16x8*)((const char*)&lds[PB][1][NH][(NI) * 64 + wn16 + cc][0] + (UX)))
#define MFMA(a, b, c) __builtin_amdgcn_mfma_f32_16x16x32_bf16(a, b, c, 0, 0, 0)

#define FENCE(DOST, SOP, SMH, PB, K0N, VN) do {                               \
    if (DOST) STAGE(SOP, SMH, (PB) ^ 1, K0N);                                 \
    __builtin_amdgcn_sched_barrier(0);                                        \
    asm volatile("s_waitcnt vmcnt(" VN ")" ::: "memory");                     \
    __builtin_amdgcn_s_barrier();                                             \
    __builtin_amdgcn_sched_barrier(0);                                        \
} while (0)

#define MMQ(MB, NB_, AHR, BHR) do {                                           \
    __builtin_amdgcn_s_setprio(1);                                            \
    _Pragma("unroll")                                                         \
    for (int kk = 0; kk < 2; ++kk)                                            \
        _Pragma("unroll")                                                     \
        for (int mi = 0; mi < 4; ++mi)                                        \
            _Pragma("unroll")                                                 \
            for (int ni = 0; ni < 2; ++ni)                                    \
                acc[(MB) + mi][(NB_) + ni] =                                  \
                    MFMA(AHR[kk][mi], BHR[kk][ni], acc[(MB) + mi][(NB_) + ni]); \
    __builtin_amdgcn_s_setprio(0);                                            \
} while (0)

#define TILE(PB, DOST, K0N, V1, V2, V3, V4) do {                              \
    _Pragma("unroll")                                                         \
    for (int kk = 0; kk < 2; ++kk) {                                          \
        const int ux = ((kk * 4 + g) ^ csw) << 4;                             \
        _Pragma("unroll")                                                     \
        for (int mi = 0; mi < 4; ++mi) aR[kk][mi] = LDA(PB, 0, mi, ux);       \
        _Pragma("unroll")                                                     \
        for (int ni = 0; ni < 2; ++ni) bR0[kk][ni] = LDB(PB, 0, ni, ux);      \
    }                                                                         \
    MMQ(0, 0, aR, bR0);                                                       \
    FENCE(DOST, 0, 0, PB, K0N, V1);                                           \
    _Pragma("unroll")                                                         \
    for (int kk = 0; kk < 2; ++kk) {                                          \
        const int ux = ((kk * 4 + g) ^ csw) << 4;                             \
        _Pragma("unroll")                                                     \
        for (int ni = 0; ni < 2; ++ni) bR1[kk][ni] = LDB(PB, 1, ni, ux);      \
    }                                                                         \
    MMQ(0, 2, aR, bR1);                                                       \
    FENCE(DOST, 1, 0, PB, K0N, V2);                                           \
    _Pragma("unroll")                                                         \
    for (int kk = 0; kk < 2; ++kk) {                                          \
        const int ux = ((kk * 4 + g) ^ csw) << 4;                             \
        _Pragma("unroll")                                                     \
        for (int mi = 0; mi < 4; ++mi) aR[kk][mi] = LDA(PB, 1, mi, ux);       \
    }                                                                         \
    MMQ(4, 2, aR, bR1);                                                       \
    FENCE(DOST, 0, 1, PB, K0N, V3);                                           \
    MMQ(4, 0, aR, bR0);                                                       \
    FENCE(DOST, 1, 1, PB, K0N, V4);                                           \
} while (0)

    STAGE(0, 0, 0, kStart);
    STAGE(1, 0, 0, kStart);
    STAGE(0, 1, 0, kStart);
    STAGE(1, 1, 0, kStart);
    __builtin_amdgcn_sched_barrier(0);
    asm volatile("s_waitcnt vmcnt(4)" ::: "memory");
    __builtin_amdgcn_s_barrier();
    __builtin_amdgcn_sched_barrier(0);

    for (int tt = 0; tt < (NT - 2) / 2; ++tt) {
        const int t0 = tt * 2;
        TILE(0, true, kStart + (t0 + 1) * 64, "2", "4", "6", "4");
        TILE(1, true, kStart + (t0 + 2) * 64, "2", "4", "6", "4");
    }
    TILE(0, true, kStart + (NT - 1) * 64, "2", "4", "6", "4");
    TILE(1, false, 0, "0", "0", "0", "0");

#undef TILE
#undef MMQ
#undef FENCE
#undef LDA
#undef LDB
#undef MFMA
#undef STAGE

    if (EPI == 0) {
        // fused RoPE epilogue; which is uniform per block (n0 is 256-aligned)
        const int which = n0 >> 11;
        const float f = (which == 0) ? 0.08838834764831845f : 1.0f;
        #pragma unroll
        for (int ai = 0; ai < 8; ai++) {
            const int rowb = m0 + (ai >> 2) * 128 + (ai & 3) * 32 + wm16 + g * 4;
            #pragma unroll
            for (int r = 0; r < 4; r++) {
                const int row = rowb + r;
                const int b = row >> 11;
                const int sidx = row & (S_LEN - 1);
                #pragma unroll
                for (int bjp = 0; bjp < 2; bjp++) {
                    const int colb0 = n0 + bjp * 128 + wn16 + cc;   // dh < 64 part
                    const int h  = (colb0 >> 7) & 15;
                    const int dh = wn16 + cc;                        // 0..63
                    const float v1 = acc[ai][2 * bjp][r]     + bias[colb0];
                    const float v2 = acc[ai][2 * bjp + 1][r] + bias[colb0 + 64];
                    float o1, o2;
                    if (which < 2) {
                        const float c  = ct[sidx * DHEAD + dh];
                        const float sn = st[sidx * DHEAD + dh];
                        o1 = (v1 * c - v2 * sn) * f;
                        o2 = (v2 * c + v1 * sn) * f;
                    } else { o1 = v1; o2 = v2; }
                    bf16* o = (bf16*)outp +
                        ((size_t)(which * 32 + b * 16 + h) * S_LEN + sidx) * DHEAD;
                    o[dh]      = __float2bfloat16(o1);
                    o[dh + 64] = __float2bfloat16(o2);
                }
            }
        }
    } else {
        #pragma unroll
        for (int ai = 0; ai < 8; ai++) {
            const int rowb = m0 + (ai >> 2) * 128 + (ai & 3) * 32 + wm16 + g * 4;
            #pragma unroll
            for (int bj = 0; bj < 4; bj++) {
                const int colb = n0 + (bj >> 1) * 128 + (bj & 1) * 64 + wn16 + cc;
                const float bcol = (EPI == 3) ? 0.0f : bias[colb];
                #pragma unroll
                for (int r = 0; r < 4; r++) {
                    const int row = rowb + r;
                    const float v = acc[ai][bj][r] + bcol;
                    if (EPI == 2) {
                        bf16* o = (bf16*)outp;
                        const float gel = 0.5f * v * (1.0f + erff(v * 0.70710678118f));
                        o[(size_t)row * N + colb] = __float2bfloat16(gel);
                    } else {
                        bf16* o = (bf16*)outp + (size_t)bz * M * N;
                        o[(size_t)row * N + colb] = __float2bfloat16(v);
                    }
                }
            }
        }
    }
}

// ---------------------------------------------------------------------------
// FF2 split-K combine (bf16 partials): out += p0 + p1 + bias
// ---------------------------------------------------------------------------
__global__ __launch_bounds__(256) void ff2_combine(const bf16* __restrict__ p,
                                                   const float* __restrict__ bias,
                                                   float* __restrict__ out) {
    const size_t i8 = (size_t)blockIdx.x * 256 + threadIdx.x;
    const size_t base = i8 * 8;
    const bf16* p0 = p + base;
    const bf16* p1 = p + (size_t)M_ROWS * D_MODEL + base;
    const int col = (int)(base & (D_MODEL - 1));
    float o[8];
    #pragma unroll
    for (int j = 0; j < 8; j++)
        o[j] = out[base + j] + __bfloat162float(p0[j]) + __bfloat162float(p1[j]) + bias[col + j];
    #pragma unroll
    for (int j = 0; j < 8; j++) out[base + j] = o[j];
}

// ---------------------------------------------------------------------------
// Flash attention, causal, max-free (unchanged).
// ---------------------------------------------------------------------------
__global__ __launch_bounds__(256) void attn_kernel(const bf16* __restrict__ q,
                                                   const bf16* __restrict__ k,
                                                   const bf16* __restrict__ vT,
                                                   bf16* __restrict__ aout) {
    int flat = blockIdx.x + gridDim.x * blockIdx.y;
    const int nwg = gridDim.x * gridDim.y;
    flat = (flat & 7) * (nwg >> 3) + (flat >> 3);
    const int qt = (int)(gridDim.x - 1 - (flat % gridDim.x));
    const int bh = flat / gridDim.x;
    const int tid = threadIdx.x;
    const int lane = tid & 63, wid = tid >> 6;
    const int cc = lane & 15, g = lane >> 4;
    const int csw = cc & 7;
    const int q0 = qt * 64;
    const int q0w = q0 + wid * 16;
    const bf16* qb = q  + (size_t)bh * S_LEN * DHEAD;
    const char* kb2 = (const char*)(k  + (size_t)bh * S_LEN * DHEAD);
    const char* vb2 = (const char*)(vT + (size_t)bh * DHEAD * S_LEN);

    __shared__ __align__(16) bf16 Ks[2][64][128];
    __shared__ __align__(16) bf16 Vs[2][128][64];
    __shared__ __align__(16) bf16 Ps[4][16][72];

    const int kst_row = wid * 4 + (lane >> 4);
    const int kst_sl  = (lane & 15) ^ (kst_row & 7);
    const int vst_row = wid * 8 + (lane >> 3);
    const int vst_sl  = (lane & 7) ^ (vst_row & 7);

    bf16x8 qf[4];
    #pragma unroll
    for (int kk = 0; kk < 4; kk++)
        qf[kk] = *(const bf16x8*)(qb + (size_t)(q0w + cc) * DHEAD + kk * 32 + g * 8);

    f32x4 oacc[8];
    const f32x4 zero = {0.f, 0.f, 0.f, 0.f};
    #pragma unroll
    for (int d = 0; d < 8; d++) oacc[d] = zero;
    float lsum[4] = {0.f, 0.f, 0.f, 0.f};

    {
        char* ksl = (char*)&Ks[0][0][0] + wid * 1024;
        char* vsl = (char*)&Vs[0][0][0] + wid * 1024;
        #pragma unroll
        for (int i = 0; i < 4; ++i) {
            gload_lds16(kb2 + (size_t)(kst_row + i * 16) * 256 + kst_sl * 16, ksl + i * 4096);
            gload_lds16(vb2 + (size_t)(vst_row + i * 32) * (S_LEN * 2) + vst_sl * 16, vsl + i * 4096);
        }
    }
    asm volatile("s_waitcnt vmcnt(0)" ::: "memory");
    __syncthreads();

    int cur = 0;
    for (int kt = 0; kt <= qt; ++kt) {
        const int kv0 = kt * 64;
        if (kt < qt) {
            const int nv0 = kv0 + 64;
            char* ksl = (char*)&Ks[cur ^ 1][0][0] + wid * 1024;
            char* vsl = (char*)&Vs[cur ^ 1][0][0] + wid * 1024;
            #pragma unroll
            for (int i = 0; i < 4; ++i) {
                gload_lds16(kb2 + (size_t)(nv0 + kst_row + i * 16) * 256 + kst_sl * 16, ksl + i * 4096);
                gload_lds16(vb2 + (size_t)(vst_row + i * 32) * (S_LEN * 2) + (size_t)nv0 * 2 + vst_sl * 16, vsl + i * 4096);
            }
        }

        f32x4 sacc[4];
        #pragma unroll
        for (int ni = 0; ni < 4; ni++) sacc[ni] = zero;
        __builtin_amdgcn_s_setprio(1);
        #pragma unroll
        for (int kk = 0; kk < 4; kk++) {
            const int ux = ((kk * 4 + g) ^ csw) << 4;
            #pragma unroll
            for (int ni = 0; ni < 4; ni++) {
                const bf16x8 kf = *(const bf16x8*)((const char*)&Ks[cur][ni * 16 + cc][0] + ux);
                sacc[ni] = __builtin_amdgcn_mfma_f32_16x16x32_bf16(qf[kk], kf, sacc[ni], 0, 0, 0);
            }
        }
        __builtin_amdgcn_s_setprio(0);

        #pragma unroll
        for (int r = 0; r < 4; r++) {
            const int qrow = q0w + g * 4 + r;
            float p[4];
            #pragma unroll
            for (int ni = 0; ni < 4; ni++) {
                const float sv = (kv0 + ni * 16 + cc <= qrow) ? sacc[ni][r] : -1e30f;
                p[ni] = __expf(sv);
            }
            lsum[r] += (p[0] + p[1]) + (p[2] + p[3]);
            #pragma unroll
            for (int ni = 0; ni < 4; ni++)
                Ps[wid][g * 4 + r][ni * 16 + cc] = __float2bfloat16(p[ni]);
        }

        __builtin_amdgcn_s_setprio(1);
        #pragma unroll
        for (int ks = 0; ks < 2; ks++) {
            const bf16x8 pf = *(const bf16x8*)(&Ps[wid][cc][ks * 32 + g * 8]);
            const int ux = ((ks * 4 + g) ^ csw) << 4;
            #pragma unroll
            for (int d = 0; d < 8; d++) {
                const bf16x8 vf = *(const bf16x8*)((const char*)&Vs[cur][d * 16 + cc][0] + ux);
                oacc[d] = __builtin_amdgcn_mfma_f32_16x16x32_bf16(pf, vf, oacc[d], 0, 0, 0);
            }
        }
        __builtin_amdgcn_s_setprio(0);

        asm volatile("s_waitcnt vmcnt(0)" ::: "memory");
        __syncthreads();
        cur ^= 1;
    }

    const int b = bh >> 4, h = bh & 15;
    #pragma unroll
    for (int r = 0; r < 4; r++) {
        float rs = lsum[r];
        #pragma unroll
        for (int off = 1; off < 16; off <<= 1) rs += __shfl_xor(rs, off);
        const float invl = 1.0f / rs;
        const int srow = q0w + g * 4 + r;
        bf16* orow = aout + ((size_t)(b * S_LEN + srow)) * D_MODEL + h * DHEAD;
        #pragma unroll
        for (int d = 0; d < 8; d++) orow[d * 16 + cc] = __float2bfloat16(oacc[d][r] * invl);
    }
}

// ---------------------------------------------------------------------------
extern "C" void kernel_launch(void* const* d_in, const int* in_sizes, int n_in,
                              void* d_out, int out_size, void* d_ws, size_t ws_size,
                              hipStream_t stream) {
    (void)in_sizes; (void)n_in; (void)out_size; (void)ws_size;
    const float* x      = (const float*)d_in[0];
    const float* cosb   = (const float*)d_in[1];
    const float* sinb   = (const float*)d_in[2];
    const float* ln1_g  = (const float*)d_in[4];
    const float* ln1_b  = (const float*)d_in[5];
    const float* w_qkv  = (const float*)d_in[6];
    const float* b_qkv  = (const float*)d_in[7];
    const float* w_out  = (const float*)d_in[8];
    const float* b_out  = (const float*)d_in[9];
    const float* ln2_g  = (const float*)d_in[10];
    const float* ln2_b  = (const float*)d_in[11];
    const float* w_ff1  = (const float*)d_in[12];
    const float* b_ff1  = (const float*)d_in[13];
    const float* w_ff2  = (const float*)d_in[14];
    const float* b_ff2  = (const float*)d_in[15];
    float* out = (float*)d_out;

    char* ws = (char*)d_ws;
    bf16* wT_qkv = (bf16*)(ws + 0);            // [6144][2048]  (dead by FF2)
    bf16* wT_out = (bf16*)(ws + 25165824);     // [2048][2048]  (dead by FF2)
    bf16* wT_ff1 = (bf16*)(ws + 33554432);     // [8192][2048]  (dead by FF2)
    bf16* wT_ff2 = (bf16*)(ws + 67108864);     // [2048][8192]
    bf16* xn     = (bf16*)(ws + 100663296);    // [4096][2048]
    bf16* qkv    = (bf16*)(ws + 117440512);    // [3][32][2048][128]
    bf16* aoutb  = (bf16*)(ws + 167772160);    // [4096][2048]
    bf16* vTb    = (bf16*)(ws + 184549376);    // [32][128][2048]
    bf16* hbuf   = (bf16*)(ws + 117440512);    // [4096][8192] aliases qkv+aoutb
    bf16* partial = (bf16*)(ws + 0);           // [2][4096][2048] bf16, FF2 split-K (wT_qkv region, dead)
    bf16* kbuf = qkv + (size_t)32 * S_LEN * DHEAD;
    bf16* vbuf = qkv + (size_t)64 * S_LEN * DHEAD;

    transpose_f2b<<<dim3(192, 64),  256, 0, stream>>>(w_qkv, wT_qkv, 2048, 6144);
    transpose_f2b<<<dim3(64, 64),   256, 0, stream>>>(w_out, wT_out, 2048, 2048);
    transpose_f2b<<<dim3(256, 64),  256, 0, stream>>>(w_ff1, wT_ff1, 2048, 8192);
    transpose_f2b<<<dim3(64, 256),  256, 0, stream>>>(w_ff2, wT_ff2, 8192, 2048);

    ln_kernel<<<M_ROWS, 256, 0, stream>>>(x, ln1_g, ln1_b, xn);
    // QKV GEMM with fused RoPE epilogue (rope_kernel eliminated)
    gemm256<0><<<dim3(24, 16), 512, 0, stream>>>(xn, wT_qkv, b_qkv, cosb, sinb, qkv, M_ROWS, 6144, 2048, 2048);
    transpose_v<<<dim3(4, 64, 32), 256, 0, stream>>>(vbuf, vTb);
    attn_kernel<<<dim3(32, 32), 256, 0, stream>>>(qkv, kbuf, vTb, aoutb);
    gemm_kernel<1><<<dim3(16, 32), 256, 0, stream>>>(aoutb, wT_out, b_out, x, out, M_ROWS, 2048, 2048, 2048);
    ln_kernel<<<M_ROWS, 256, 0, stream>>>(out, ln2_g, ln2_b, xn);
    gemm256<2><<<dim3(32, 16), 512, 0, stream>>>(xn, wT_ff1, b_ff1, nullptr, nullptr, hbuf, M_ROWS, DFF, 2048, 2048);
    gemm256<3><<<dim3(8, 16, 2), 512, 0, stream>>>(hbuf, wT_ff2, nullptr, nullptr, nullptr, partial, M_ROWS, 2048, 8192, 4096);
    ff2_combine<<<4096, 256, 0, stream>>>(partial, b_ff2, out);
}